// Round 1
// baseline (2344.868 us; speedup 1.0000x reference)
//
#include <hip/hip_runtime.h>
#include <hip/hip_bf16.h>
#include <cstdint>

#define D_MODEL 1024
#define NHEADS  16
#define DK      64
#define BATCH   4
#define SEQ     2048
#define MROWS   (BATCH * SEQ)   // 8192

typedef __attribute__((ext_vector_type(4))) float  f32x4;
typedef __attribute__((ext_vector_type(8))) __bf16 bf16x8;
typedef __attribute__((ext_vector_type(8))) short  short8;

__device__ __forceinline__ float bf2f(unsigned short u) {
    return __uint_as_float(((unsigned int)u) << 16);
}
__device__ __forceinline__ unsigned short f2bf(float f) {
    unsigned int u = __float_as_uint(f);
    unsigned int r = (u + 0x7fffu + ((u >> 16) & 1u)) >> 16;
    return (unsigned short)r;
}

// ---------------- fp32 -> bf16 conversion ----------------
__global__ void cvt_bf16(const float* __restrict__ in, unsigned short* __restrict__ out, int n) {
    int i = (blockIdx.x * 256 + threadIdx.x) * 4;
    if (i >= n) return;
    float4 v = *reinterpret_cast<const float4*>(in + i);
    ushort4 o;
    o.x = f2bf(v.x); o.y = f2bf(v.y); o.z = f2bf(v.z); o.w = f2bf(v.w);
    *reinterpret_cast<ushort4*>(out + i) = o;
}

// ---------------- async global->LDS (16B per lane) ----------------
__device__ __forceinline__ void gload_lds16(const void* g, void* l) {
    __builtin_amdgcn_global_load_lds(
        (const __attribute__((address_space(1))) void*)(uintptr_t)g,
        (__attribute__((address_space(3))) void*)(unsigned int)(uintptr_t)l,
        16, 0, 0);
}

// ---------------- bf16 MFMA GEMM: C[M][N] = A[M][K] * Bt[N][K]^T ----------------
#define BM 128
#define BN 128
#define BK 32

__global__ __launch_bounds__(256) void gemm_bt(
    const unsigned short* __restrict__ A,
    const unsigned short* __restrict__ B0,
    const unsigned short* __restrict__ B1,
    const unsigned short* __restrict__ B2,
    void* __restrict__ C0, void* __restrict__ C1, void* __restrict__ C2,
    int M, int N, int K, int out_f32)
{
    __shared__ __align__(16) unsigned short As[BM * BK];
    __shared__ __align__(16) unsigned short Bs[BN * BK];

    const int z = blockIdx.z;
    const unsigned short* Bt = (z == 0) ? B0 : ((z == 1) ? B1 : B2);
    void* C = (z == 0) ? C0 : ((z == 1) ? C1 : C2);

    const int tid  = threadIdx.x;
    const int wave = tid >> 6;
    const int lane = tid & 63;
    const int wr   = wave >> 1;   // 0..1
    const int wc   = wave & 1;    // 0..1
    const int bm   = blockIdx.x * BM;
    const int bn   = blockIdx.y * BN;

    f32x4 acc[4][4];
    for (int i = 0; i < 4; i++)
        for (int j = 0; j < 4; j++)
            for (int r = 0; r < 4; r++) acc[i][j][r] = 0.f;

    // staging geometry: 256 threads x 8 bf16 (16B) per issue; 2 issues per tile
    const int srow = tid >> 2;          // (tid*8)/32: 0..63
    const int scol = (tid & 3) * 8;     // 0,8,16,24

    const int kg = (lane >> 4) * 8;     // k-offset of this lane's fragment
    const int rl = lane & 15;

    for (int k0 = 0; k0 < K; k0 += BK) {
        __syncthreads();
        gload_lds16(A  + (size_t)(bm + srow)      * K + k0 + scol, As + wave * 512);
        gload_lds16(A  + (size_t)(bm + 64 + srow) * K + k0 + scol, As + 2048 + wave * 512);
        gload_lds16(Bt + (size_t)(bn + srow)      * K + k0 + scol, Bs + wave * 512);
        gload_lds16(Bt + (size_t)(bn + 64 + srow) * K + k0 + scol, Bs + 2048 + wave * 512);
        __syncthreads();

        bf16x8 a[4], b[4];
        for (int mi = 0; mi < 4; mi++) {
            short8 t = *reinterpret_cast<const short8*>(&As[(wr * 64 + mi * 16 + rl) * BK + kg]);
            a[mi] = __builtin_bit_cast(bf16x8, t);
        }
        for (int ni = 0; ni < 4; ni++) {
            short8 t = *reinterpret_cast<const short8*>(&Bs[(wc * 64 + ni * 16 + rl) * BK + kg]);
            b[ni] = __builtin_bit_cast(bf16x8, t);
        }
        for (int mi = 0; mi < 4; mi++)
            for (int ni = 0; ni < 4; ni++)
                acc[mi][ni] = __builtin_amdgcn_mfma_f32_16x16x32_bf16(a[mi], b[ni], acc[mi][ni], 0, 0, 0);
    }

    const int rg = (lane >> 4) * 4;
    for (int mi = 0; mi < 4; mi++)
        for (int ni = 0; ni < 4; ni++)
            for (int r = 0; r < 4; r++) {
                int row = bm + wr * 64 + mi * 16 + rg + r;
                int col = bn + wc * 64 + ni * 16 + rl;
                float v = acc[mi][ni][r];
                if (out_f32) ((float*)C)[(size_t)row * N + col] = v;
                else         ((unsigned short*)C)[(size_t)row * N + col] = f2bf(v);
            }
}

// ---------------- causal flash attention (vector fp32) ----------------
// Q,K,V,O: bf16 [B*S][D_MODEL]; head h occupies cols h*64..h*64+63
__device__ __forceinline__ void unpack8(uint4 t, float* f) {
    unsigned int w0 = t.x, w1 = t.y, w2 = t.z, w3 = t.w;
    f[0] = __uint_as_float((w0 & 0xffffu) << 16); f[1] = __uint_as_float(w0 & 0xffff0000u);
    f[2] = __uint_as_float((w1 & 0xffffu) << 16); f[3] = __uint_as_float(w1 & 0xffff0000u);
    f[4] = __uint_as_float((w2 & 0xffffu) << 16); f[5] = __uint_as_float(w2 & 0xffff0000u);
    f[6] = __uint_as_float((w3 & 0xffffu) << 16); f[7] = __uint_as_float(w3 & 0xffff0000u);
}

__global__ __launch_bounds__(256) void attn_fwd(
    const unsigned short* __restrict__ Q,
    const unsigned short* __restrict__ K,
    const unsigned short* __restrict__ V,
    unsigned short* __restrict__ O)
{
    __shared__ __align__(16) unsigned short Ks[32 * 64];
    __shared__ __align__(16) unsigned short Vs[32 * 64];

    const int bh = blockIdx.x;            // b*16 + h
    const int b  = bh >> 4;
    const int h  = bh & 15;
    const int qt = blockIdx.y;
    const int tid = threadIdx.x;
    const int ql = tid >> 3;              // 0..31 q row within tile
    const int dc = tid & 7;               // 0..7 d-chunk (8 floats each)
    const int q  = qt * 32 + ql;

    const size_t headbase = ((size_t)b * SEQ) * D_MODEL + h * DK;

    float qreg[8];
    {
        uint4 t = *reinterpret_cast<const uint4*>(&Q[headbase + (size_t)q * D_MODEL + dc * 8]);
        unpack8(t, qreg);
    }

    float acc[8];
    for (int j = 0; j < 8; j++) acc[j] = 0.f;
    float m_run = -INFINITY, l_run = 0.f;

    const int smm = tid >> 3;             // staging row 0..31
    const int sdd = (tid & 7) * 8;        // staging col

    for (int m0 = 0; m0 <= qt * 32; m0 += 32) {
        *reinterpret_cast<uint4*>(&Ks[smm * 64 + sdd]) =
            *reinterpret_cast<const uint4*>(&K[headbase + (size_t)(m0 + smm) * D_MODEL + sdd]);
        *reinterpret_cast<uint4*>(&Vs[smm * 64 + sdd]) =
            *reinterpret_cast<const uint4*>(&V[headbase + (size_t)(m0 + smm) * D_MODEL + sdd]);
        __syncthreads();

        for (int mm = 0; mm < 32; mm++) {
            uint4 kk = *reinterpret_cast<const uint4*>(&Ks[mm * 64 + dc * 8]);
            float kf[8]; unpack8(kk, kf);
            float part = 0.f;
            for (int j = 0; j < 8; j++) part += qreg[j] * kf[j];
            part += __shfl_xor(part, 1);
            part += __shfl_xor(part, 2);
            part += __shfl_xor(part, 4);
            float s = part * 0.125f;                 // 1/sqrt(64)
            if (m0 + mm > q) s = -INFINITY;
            float mnew = fmaxf(m_run, s);
            float sc = __expf(m_run - mnew);
            float p  = __expf(s - mnew);
            l_run = l_run * sc + p;
            uint4 vv = *reinterpret_cast<const uint4*>(&Vs[mm * 64 + dc * 8]);
            float vf[8]; unpack8(vv, vf);
            for (int j = 0; j < 8; j++) acc[j] = acc[j] * sc + p * vf[j];
            m_run = mnew;
        }
        __syncthreads();
    }

    float inv = 1.0f / l_run;
    unsigned short ob[8];
    for (int j = 0; j < 8; j++) ob[j] = f2bf(acc[j] * inv);
    *reinterpret_cast<uint4*>(&O[headbase + (size_t)q * D_MODEL + dc * 8]) =
        *reinterpret_cast<uint4*>(ob);
}

// ---------------- launch ----------------
extern "C" void kernel_launch(void* const* d_in, const int* in_sizes, int n_in,
                              void* d_out, int out_size, void* d_ws, size_t ws_size,
                              hipStream_t stream) {
    const float* x  = (const float*)d_in[0];
    const float* wq = (const float*)d_in[1];
    const float* wk = (const float*)d_in[2];
    const float* wv = (const float*)d_in[3];
    const float* wo = (const float*)d_in[4];

    char* ws = (char*)d_ws;
    const size_t NXB = (size_t)MROWS * D_MODEL * 2;   // 16 MiB bf16 x
    const size_t NWB = (size_t)D_MODEL * D_MODEL * 2; // 2 MiB bf16 weight

    unsigned short* xb  = (unsigned short*)(ws);
    unsigned short* wqb = (unsigned short*)(ws + NXB);
    unsigned short* wkb = (unsigned short*)(ws + NXB + NWB);
    unsigned short* wvb = (unsigned short*)(ws + NXB + 2 * NWB);
    unsigned short* wob = (unsigned short*)(ws + NXB + 3 * NWB);
    unsigned short* Qb  = (unsigned short*)(ws + NXB + 4 * NWB);
    unsigned short* Kb  = (unsigned short*)(ws + NXB + 4 * NWB + NXB);
    unsigned short* Vb  = (unsigned short*)(ws + NXB + 4 * NWB + 2 * NXB);
    unsigned short* Ab  = (unsigned short*)(ws + NXB + 4 * NWB + 3 * NXB);

    const int NX = MROWS * D_MODEL;       // 8388608
    const int NW = D_MODEL * D_MODEL;     // 1048576

    cvt_bf16<<<NX / 1024, 256, 0, stream>>>(x,  xb,  NX);
    cvt_bf16<<<NW / 1024, 256, 0, stream>>>(wq, wqb, NW);
    cvt_bf16<<<NW / 1024, 256, 0, stream>>>(wk, wkb, NW);
    cvt_bf16<<<NW / 1024, 256, 0, stream>>>(wv, wvb, NW);
    cvt_bf16<<<NW / 1024, 256, 0, stream>>>(wo, wob, NW);

    dim3 gqkv(MROWS / BM, D_MODEL / BN, 3);
    gemm_bt<<<gqkv, 256, 0, stream>>>(xb, wqb, wkb, wvb, Qb, Kb, Vb,
                                      MROWS, D_MODEL, D_MODEL, 0);

    dim3 gattn(BATCH * NHEADS, SEQ / 32, 1);
    attn_fwd<<<gattn, 256, 0, stream>>>(Qb, Kb, Vb, Ab);

    dim3 gout(MROWS / BM, D_MODEL / BN, 1);
    gemm_bt<<<gout, 256, 0, stream>>>(Ab, wob, wob, wob, d_out, d_out, d_out,
                                      MROWS, D_MODEL, D_MODEL, 1);
}

// Round 2
// 785.295 us; speedup vs baseline: 2.9860x; 2.9860x over previous
//
#include <hip/hip_runtime.h>
#include <hip/hip_bf16.h>
#include <cstdint>

#define D_MODEL 1024
#define NHEADS  16
#define DK      64
#define BATCH   4
#define SEQ     2048
#define MROWS   (BATCH * SEQ)   // 8192

typedef __attribute__((ext_vector_type(4))) float  f32x4;
typedef __attribute__((ext_vector_type(8))) __bf16 bf16x8;
typedef __attribute__((ext_vector_type(8))) short  short8;

__device__ __forceinline__ unsigned short f2bf(float f) {
    unsigned int u = __float_as_uint(f);
    unsigned int r = (u + 0x7fffu + ((u >> 16) & 1u)) >> 16;
    return (unsigned short)r;
}

__device__ __forceinline__ unsigned int cvtpk_bf16(float lo, float hi) {
    unsigned int r;
    asm volatile("v_cvt_pk_bf16_f32 %0, %1, %2" : "=v"(r) : "v"(lo), "v"(hi));
    return r;
}

// ---------------- fp32 -> bf16 conversion ----------------
__global__ void cvt_bf16(const float* __restrict__ in, unsigned short* __restrict__ out, int n) {
    int i = (blockIdx.x * 256 + threadIdx.x) * 4;
    if (i >= n) return;
    float4 v = *reinterpret_cast<const float4*>(in + i);
    ushort4 o;
    o.x = f2bf(v.x); o.y = f2bf(v.y); o.z = f2bf(v.z); o.w = f2bf(v.w);
    *reinterpret_cast<ushort4*>(out + i) = o;
}

// ---------------- async global->LDS (16B per lane) ----------------
__device__ __forceinline__ void gload_lds16(const void* g, void* l) {
    __builtin_amdgcn_global_load_lds(
        (const __attribute__((address_space(1))) void*)(uintptr_t)g,
        (__attribute__((address_space(3))) void*)(unsigned int)(uintptr_t)l,
        16, 0, 0);
}

// ---------------- bf16 MFMA GEMM: C[M][N] = A[M][K] * Bt[N][K]^T ----------------
#define BM 128
#define BN 128
#define BK 32

__global__ __launch_bounds__(256) void gemm_bt(
    const unsigned short* __restrict__ A,
    const unsigned short* __restrict__ B0,
    const unsigned short* __restrict__ B1,
    const unsigned short* __restrict__ B2,
    void* __restrict__ C0, void* __restrict__ C1, void* __restrict__ C2,
    int M, int N, int K, int out_f32)
{
    __shared__ __align__(16) unsigned short As[BM * BK];
    __shared__ __align__(16) unsigned short Bs[BN * BK];

    const int z = blockIdx.z;
    const unsigned short* Bt = (z == 0) ? B0 : ((z == 1) ? B1 : B2);
    void* C = (z == 0) ? C0 : ((z == 1) ? C1 : C2);

    const int tid  = threadIdx.x;
    const int wave = tid >> 6;
    const int lane = tid & 63;
    const int wr   = wave >> 1;   // 0..1
    const int wc   = wave & 1;    // 0..1
    const int bm   = blockIdx.x * BM;
    const int bn   = blockIdx.y * BN;

    f32x4 acc[4][4];
    for (int i = 0; i < 4; i++)
        for (int j = 0; j < 4; j++)
            for (int r = 0; r < 4; r++) acc[i][j][r] = 0.f;

    const int srow = tid >> 2;          // 0..63
    const int scol = (tid & 3) * 8;     // 0,8,16,24

    const int kg = (lane >> 4) * 8;
    const int rl = lane & 15;

    for (int k0 = 0; k0 < K; k0 += BK) {
        __syncthreads();
        gload_lds16(A  + (size_t)(bm + srow)      * K + k0 + scol, As + wave * 512);
        gload_lds16(A  + (size_t)(bm + 64 + srow) * K + k0 + scol, As + 2048 + wave * 512);
        gload_lds16(Bt + (size_t)(bn + srow)      * K + k0 + scol, Bs + wave * 512);
        gload_lds16(Bt + (size_t)(bn + 64 + srow) * K + k0 + scol, Bs + 2048 + wave * 512);
        __syncthreads();

        bf16x8 a[4], b[4];
        for (int mi = 0; mi < 4; mi++) {
            short8 t = *reinterpret_cast<const short8*>(&As[(wr * 64 + mi * 16 + rl) * BK + kg]);
            a[mi] = __builtin_bit_cast(bf16x8, t);
        }
        for (int ni = 0; ni < 4; ni++) {
            short8 t = *reinterpret_cast<const short8*>(&Bs[(wc * 64 + ni * 16 + rl) * BK + kg]);
            b[ni] = __builtin_bit_cast(bf16x8, t);
        }
        for (int mi = 0; mi < 4; mi++)
            for (int ni = 0; ni < 4; ni++)
                acc[mi][ni] = __builtin_amdgcn_mfma_f32_16x16x32_bf16(a[mi], b[ni], acc[mi][ni], 0, 0, 0);
    }

    const int rg = (lane >> 4) * 4;
    for (int mi = 0; mi < 4; mi++)
        for (int ni = 0; ni < 4; ni++)
            for (int r = 0; r < 4; r++) {
                int row = bm + wr * 64 + mi * 16 + rg + r;
                int col = bn + wc * 64 + ni * 16 + rl;
                float v = acc[mi][ni][r];
                if (out_f32) ((float*)C)[(size_t)row * N + col] = v;
                else         ((unsigned short*)C)[(size_t)row * N + col] = f2bf(v);
            }
}

// ---------------- MFMA causal flash attention ----------------
// Q,K,V,O: bf16 [B*S][D_MODEL]; head h = cols h*64..h*64+63
// Block: 4 waves; wave w owns q rows [qt*64 + w*16, +16).
// KV tiles of 64 keys. Swapped QK^T: lane holds P-row for q = lane&15.
__global__ __launch_bounds__(256) void attn_mfma(
    const unsigned short* __restrict__ Q,
    const unsigned short* __restrict__ K,
    const unsigned short* __restrict__ V,
    unsigned short* __restrict__ O)
{
    __shared__ __align__(16) unsigned short Ks[64 * 64];  // [key][d], col-slot XOR-swizzled
    __shared__ __align__(16) unsigned short Vt[64 * 64];  // [d][key], col XOR-swizzled

    const int bh  = blockIdx.x;
    const int b   = bh >> 4;
    const int h   = bh & 15;
    const int qt  = blockIdx.y;
    const int tid = threadIdx.x;
    const int wave = tid >> 6;
    const int lane = tid & 63;
    const int lg   = lane >> 4;    // lane group 0..3
    const int lq   = lane & 15;

    const size_t base = ((size_t)b * SEQ) * D_MODEL + h * DK;
    const int q0  = qt * 64;
    const int qw  = q0 + wave * 16;     // wave's q-row base
    const int myq = qw + lq;            // the q row this lane softmaxes

    // Q fragment (B-operand of QK^T): row=q=lq, k = ks*32 + lg*8 + j
    bf16x8 qf[2];
    {
        const unsigned short* qp = Q + base + (size_t)myq * D_MODEL + lg * 8;
        qf[0] = __builtin_bit_cast(bf16x8, *reinterpret_cast<const short8*>(qp));
        qf[1] = __builtin_bit_cast(bf16x8, *reinterpret_cast<const short8*>(qp + 32));
    }

    f32x4 acc[4];   // [dg]: O[q_local = lg*4+reg][d = dg*16+lq]
    for (int i = 0; i < 4; i++)
        for (int r = 0; r < 4; r++) acc[i][r] = 0.f;
    float m_run = -INFINITY, l_run = 0.f;

    const int trow  = tid >> 3;       // K staging row 0..31
    const int tslot = tid & 7;        // K staging 16B slot

    const int nt = qt + 1;
    for (int t = 0; t < nt; ++t) {
        const int m0 = t * 64;
        __syncthreads();   // previous tile's compute done

        // ---- stage K tile via global_load_lds, source pre-swizzled (slot ^= row&7) ----
        {
            const int c0 = (tslot ^ (trow & 7)) * 8;
            gload_lds16(K + base + (size_t)(m0 + trow) * D_MODEL + c0, Ks + wave * 512);
            const int r1 = trow + 32;
            const int c1 = (tslot ^ (r1 & 7)) * 8;
            gload_lds16(K + base + (size_t)(m0 + r1) * D_MODEL + c1, Ks + 2048 + wave * 512);
        }
        // ---- stage V transposed: Vt[d][key], byte col ^= (d&7)<<4 ----
        for (int p = 0; p < 2; ++p) {
            const int d0 = wave * 8 + p * 32;
            union { uint4 v; unsigned short u[8]; } vb;
            vb.v = *reinterpret_cast<const uint4*>(V + base + (size_t)(m0 + lane) * D_MODEL + d0);
            #pragma unroll
            for (int e = 0; e < 8; ++e) {
                const int d = d0 + e;
                const int addr = d * 128 + ((lane * 2) ^ ((d & 7) << 4));
                *reinterpret_cast<unsigned short*>((char*)Vt + addr) = vb.u[e];
            }
        }
        __syncthreads();   // staging visible

        // ---- QK^T (swapped): s[kg] row=key=kg*16+lg*4+reg, col=q=lq ----
        f32x4 s[4];
        #pragma unroll
        for (int kg = 0; kg < 4; ++kg) {
            for (int r = 0; r < 4; ++r) s[kg][r] = 0.f;
            #pragma unroll
            for (int ks = 0; ks < 2; ++ks) {
                const int row  = kg * 16 + lq;
                const int slot = (ks * 4 + lg) ^ (row & 7);
                bf16x8 kf = __builtin_bit_cast(bf16x8,
                    *reinterpret_cast<const short8*>((const char*)Ks + row * 128 + slot * 16));
                s[kg] = __builtin_amdgcn_mfma_f32_16x16x32_bf16(kf, qf[ks], s[kg], 0, 0, 0);
            }
        }

        // ---- online softmax (per lane: q = myq, 16 keys in regs) ----
        float sv[4][4];
        float mx = -INFINITY;
        #pragma unroll
        for (int kg = 0; kg < 4; ++kg)
            #pragma unroll
            for (int r = 0; r < 4; ++r) {
                const int key = m0 + kg * 16 + lg * 4 + r;
                float v = s[kg][r] * 0.125f;
                if (key > myq) v = -INFINITY;
                sv[kg][r] = v;
                mx = fmaxf(mx, v);
            }
        mx = fmaxf(mx, __shfl_xor(mx, 16));
        mx = fmaxf(mx, __shfl_xor(mx, 32));
        const float mnew = fmaxf(m_run, mx);
        const float sc   = __expf(m_run - mnew);
        m_run = mnew;

        float p[4][4];
        float ps = 0.f;
        #pragma unroll
        for (int kg = 0; kg < 4; ++kg)
            #pragma unroll
            for (int r = 0; r < 4; ++r) {
                p[kg][r] = __expf(sv[kg][r] - mnew);
                ps += p[kg][r];
            }
        ps += __shfl_xor(ps, 16);
        ps += __shfl_xor(ps, 32);
        l_run = l_run * sc + ps;

        // rescale O accumulator: scale for q_local = lg*4+r lives on lane (lg*4+r)
        float scv[4];
        #pragma unroll
        for (int r = 0; r < 4; ++r) scv[r] = __shfl(sc, lg * 4 + r);
        #pragma unroll
        for (int dg = 0; dg < 4; ++dg)
            #pragma unroll
            for (int r = 0; r < 4; ++r) acc[dg][r] *= scv[r];

        // ---- redistribute P into A-frag layout + PV ----
        #pragma unroll
        for (int ks = 0; ks < 2; ++ks) {
            // packed pairs: wlo* from kg=2ks (local keys 4lg+{0,1},{2,3}),
            //               whi* from kg=2ks+1 (local keys 16+4lg+{0,1},{2,3})
            const unsigned int wlo0 = cvtpk_bf16(p[2*ks][0],   p[2*ks][1]);
            const unsigned int wlo1 = cvtpk_bf16(p[2*ks][2],   p[2*ks][3]);
            const unsigned int whi0 = cvtpk_bf16(p[2*ks+1][0], p[2*ks+1][1]);
            const unsigned int whi1 = cvtpk_bf16(p[2*ks+1][2], p[2*ks+1][3]);
            unsigned int aw[4];
            #pragma unroll
            for (int w = 0; w < 4; ++w) {
                // dest needs local keys 8*lg + 2w,2w+1
                const int src = lq + (((lg & 1) * 2 + (w >> 1)) << 4);
                const unsigned int t0 = __shfl((w & 1) ? wlo1 : wlo0, src);
                const unsigned int t1 = __shfl((w & 1) ? whi1 : whi0, src);
                aw[w] = (lg < 2) ? t0 : t1;
            }
            uint4 awv = make_uint4(aw[0], aw[1], aw[2], aw[3]);
            bf16x8 af = __builtin_bit_cast(bf16x8, awv);
            #pragma unroll
            for (int dg = 0; dg < 4; ++dg) {
                const int d = dg * 16 + lq;
                const int addr = d * 128 + ((ks * 64 + lg * 16) ^ ((d & 7) << 4));
                bf16x8 vf = __builtin_bit_cast(bf16x8,
                    *reinterpret_cast<const short8*>((const char*)Vt + addr));
                acc[dg] = __builtin_amdgcn_mfma_f32_16x16x32_bf16(af, vf, acc[dg], 0, 0, 0);
            }
        }
    }

    // ---- epilogue: divide by l and store ----
    float lv[4];
    #pragma unroll
    for (int r = 0; r < 4; ++r) lv[r] = 1.0f / __shfl(l_run, lg * 4 + r);
    #pragma unroll
    for (int dg = 0; dg < 4; ++dg)
        #pragma unroll
        for (int r = 0; r < 4; ++r) {
            const int qrow = qw + lg * 4 + r;
            O[base + (size_t)qrow * D_MODEL + dg * 16 + lq] = f2bf(acc[dg][r] * lv[r]);
        }
}

// ---------------- launch ----------------
extern "C" void kernel_launch(void* const* d_in, const int* in_sizes, int n_in,
                              void* d_out, int out_size, void* d_ws, size_t ws_size,
                              hipStream_t stream) {
    const float* x  = (const float*)d_in[0];
    const float* wq = (const float*)d_in[1];
    const float* wk = (const float*)d_in[2];
    const float* wv = (const float*)d_in[3];
    const float* wo = (const float*)d_in[4];

    char* ws = (char*)d_ws;
    const size_t NXB = (size_t)MROWS * D_MODEL * 2;   // 16 MiB bf16 x
    const size_t NWB = (size_t)D_MODEL * D_MODEL * 2; // 2 MiB bf16 weight

    unsigned short* xb  = (unsigned short*)(ws);
    unsigned short* wqb = (unsigned short*)(ws + NXB);
    unsigned short* wkb = (unsigned short*)(ws + NXB + NWB);
    unsigned short* wvb = (unsigned short*)(ws + NXB + 2 * NWB);
    unsigned short* wob = (unsigned short*)(ws + NXB + 3 * NWB);
    unsigned short* Qb  = (unsigned short*)(ws + NXB + 4 * NWB);
    unsigned short* Kb  = (unsigned short*)(ws + NXB + 4 * NWB + NXB);
    unsigned short* Vb  = (unsigned short*)(ws + NXB + 4 * NWB + 2 * NXB);
    unsigned short* Ab  = (unsigned short*)(ws + NXB + 4 * NWB + 3 * NXB);

    const int NX = MROWS * D_MODEL;
    const int NW = D_MODEL * D_MODEL;

    cvt_bf16<<<NX / 1024, 256, 0, stream>>>(x,  xb,  NX);
    cvt_bf16<<<NW / 1024, 256, 0, stream>>>(wq, wqb, NW);
    cvt_bf16<<<NW / 1024, 256, 0, stream>>>(wk, wkb, NW);
    cvt_bf16<<<NW / 1024, 256, 0, stream>>>(wv, wvb, NW);
    cvt_bf16<<<NW / 1024, 256, 0, stream>>>(wo, wob, NW);

    dim3 gqkv(MROWS / BM, D_MODEL / BN, 3);
    gemm_bt<<<gqkv, 256, 0, stream>>>(xb, wqb, wkb, wvb, Qb, Kb, Vb,
                                      MROWS, D_MODEL, D_MODEL, 0);

    dim3 gattn(BATCH * NHEADS, SEQ / 64, 1);
    attn_mfma<<<gattn, 256, 0, stream>>>(Qb, Kb, Vb, Ab);

    dim3 gout(MROWS / BM, D_MODEL / BN, 1);
    gemm_bt<<<gout, 256, 0, stream>>>(Ab, wob, wob, wob, d_out, d_out, d_out,
                                      MROWS, D_MODEL, D_MODEL, 1);
}

// Round 3
// 760.420 us; speedup vs baseline: 3.0836x; 1.0327x over previous
//
#include <hip/hip_runtime.h>
#include <hip/hip_bf16.h>
#include <cstdint>

#define D_MODEL 1024
#define NHEADS  16
#define DK      64
#define BATCH   4
#define SEQ     2048
#define MROWS   (BATCH * SEQ)   // 8192

typedef __attribute__((ext_vector_type(4))) float  f32x4;
typedef __attribute__((ext_vector_type(8))) __bf16 bf16x8;
typedef __attribute__((ext_vector_type(8))) short  short8;

__device__ __forceinline__ unsigned short f2bf(float f) {
    unsigned int u = __float_as_uint(f);
    unsigned int r = (u + 0x7fffu + ((u >> 16) & 1u)) >> 16;
    return (unsigned short)r;
}

__device__ __forceinline__ unsigned int cvtpk_bf16(float lo, float hi) {
    unsigned int r;
    asm volatile("v_cvt_pk_bf16_f32 %0, %1, %2" : "=v"(r) : "v"(lo), "v"(hi));
    return r;
}

// ---------------- fp32 -> bf16 conversion ----------------
__global__ void cvt_bf16(const float* __restrict__ in, unsigned short* __restrict__ out, int n) {
    int i = (blockIdx.x * 256 + threadIdx.x) * 4;
    if (i >= n) return;
    float4 v = *reinterpret_cast<const float4*>(in + i);
    ushort4 o;
    o.x = f2bf(v.x); o.y = f2bf(v.y); o.z = f2bf(v.z); o.w = f2bf(v.w);
    *reinterpret_cast<ushort4*>(out + i) = o;
}

// 4 weights in one launch: grid.y selects the weight
__global__ void cvt_bf16_w(const float* __restrict__ w0, const float* __restrict__ w1,
                           const float* __restrict__ w2, const float* __restrict__ w3,
                           unsigned short* __restrict__ o0, unsigned short* __restrict__ o1,
                           unsigned short* __restrict__ o2, unsigned short* __restrict__ o3,
                           int n) {
    const int z = blockIdx.y;
    const float* in = (z == 0) ? w0 : (z == 1) ? w1 : (z == 2) ? w2 : w3;
    unsigned short* out = (z == 0) ? o0 : (z == 1) ? o1 : (z == 2) ? o2 : o3;
    int i = (blockIdx.x * 256 + threadIdx.x) * 4;
    if (i >= n) return;
    float4 v = *reinterpret_cast<const float4*>(in + i);
    ushort4 o;
    o.x = f2bf(v.x); o.y = f2bf(v.y); o.z = f2bf(v.z); o.w = f2bf(v.w);
    *reinterpret_cast<ushort4*>(out + i) = o;
}

// ---------------- async global->LDS (16B per lane) ----------------
__device__ __forceinline__ void gload_lds16(const void* g, void* l) {
    __builtin_amdgcn_global_load_lds(
        (const __attribute__((address_space(1))) void*)(uintptr_t)g,
        (__attribute__((address_space(3))) void*)(unsigned int)(uintptr_t)l,
        16, 0, 0);
}

// ---------------- bf16 MFMA GEMM, 2-phase double-buffered pipeline ----------------
// C[M][N] = A[M][K] * Bt[N][K]^T
#define BM 128
#define BN 128
#define BK 32

__global__ __launch_bounds__(256) void gemm_bt(
    const unsigned short* __restrict__ A,
    const unsigned short* __restrict__ B0,
    const unsigned short* __restrict__ B1,
    const unsigned short* __restrict__ B2,
    void* __restrict__ C0, void* __restrict__ C1, void* __restrict__ C2,
    int M, int N, int K, int out_f32)
{
    // double-buffered: 2 x (128x32 A + 128x32 B) bf16 = 32 KiB total
    __shared__ __align__(16) unsigned short As[2][BM * BK];
    __shared__ __align__(16) unsigned short Bs[2][BN * BK];

    const int z = blockIdx.z;
    const unsigned short* Bt = (z == 0) ? B0 : ((z == 1) ? B1 : B2);
    void* C = (z == 0) ? C0 : ((z == 1) ? C1 : C2);

    const int tid  = threadIdx.x;
    const int wave = tid >> 6;
    const int lane = tid & 63;
    const int wr   = wave >> 1;   // 0..1
    const int wc   = wave & 1;    // 0..1
    const int bm   = blockIdx.x * BM;
    const int bn   = blockIdx.y * BN;

    f32x4 acc[4][4];
    for (int i = 0; i < 4; i++)
        for (int j = 0; j < 4; j++)
            for (int r = 0; r < 4; r++) acc[i][j][r] = 0.f;

    const int srow = tid >> 2;          // 0..63
    const int scol = (tid & 3) * 8;     // 0,8,16,24

    const int kg = (lane >> 4) * 8;
    const int rl = lane & 15;

    const unsigned short* Arow0 = A  + (size_t)(bm + srow) * K + scol;
    const unsigned short* Arow1 = A  + (size_t)(bm + 64 + srow) * K + scol;
    const unsigned short* Brow0 = Bt + (size_t)(bn + srow) * K + scol;
    const unsigned short* Brow1 = Bt + (size_t)(bn + 64 + srow) * K + scol;

    auto STAGE = [&](int buf, int k0) {
        gload_lds16(Arow0 + k0, &As[buf][0] + wave * 512);
        gload_lds16(Arow1 + k0, &As[buf][0] + 2048 + wave * 512);
        gload_lds16(Brow0 + k0, &Bs[buf][0] + wave * 512);
        gload_lds16(Brow1 + k0, &Bs[buf][0] + 2048 + wave * 512);
    };

    auto COMPUTE = [&](int buf) {
        bf16x8 a[4], b[4];
        #pragma unroll
        for (int mi = 0; mi < 4; mi++) {
            short8 t = *reinterpret_cast<const short8*>(&As[buf][(wr * 64 + mi * 16 + rl) * BK + kg]);
            a[mi] = __builtin_bit_cast(bf16x8, t);
        }
        #pragma unroll
        for (int ni = 0; ni < 4; ni++) {
            short8 t = *reinterpret_cast<const short8*>(&Bs[buf][(wc * 64 + ni * 16 + rl) * BK + kg]);
            b[ni] = __builtin_bit_cast(bf16x8, t);
        }
        #pragma unroll
        for (int mi = 0; mi < 4; mi++)
            #pragma unroll
            for (int ni = 0; ni < 4; ni++)
                acc[mi][ni] = __builtin_amdgcn_mfma_f32_16x16x32_bf16(a[mi], b[ni], acc[mi][ni], 0, 0, 0);
    };

    const int NT = K / BK;

    // prologue: stage tile 0 into buf 0 (compiler drains vmcnt before s_barrier)
    STAGE(0, 0);
    __syncthreads();

    int cur = 0;
    for (int t = 0; t < NT - 1; ++t) {
        STAGE(cur ^ 1, (t + 1) * BK);   // async prefetch overlaps with compute below
        COMPUTE(cur);
        __syncthreads();                 // drains staging loads; next buf ready
        cur ^= 1;
    }
    COMPUTE(cur);

    const int rg = (lane >> 4) * 4;
    for (int mi = 0; mi < 4; mi++)
        for (int ni = 0; ni < 4; ni++)
            for (int r = 0; r < 4; r++) {
                int row = bm + wr * 64 + mi * 16 + rg + r;
                int col = bn + wc * 64 + ni * 16 + rl;
                float v = acc[mi][ni][r];
                if (out_f32) ((float*)C)[(size_t)row * N + col] = v;
                else         ((unsigned short*)C)[(size_t)row * N + col] = f2bf(v);
            }
}

// ---------------- MFMA causal flash attention (unchanged from round 2) ----------------
__global__ __launch_bounds__(256) void attn_mfma(
    const unsigned short* __restrict__ Q,
    const unsigned short* __restrict__ K,
    const unsigned short* __restrict__ V,
    unsigned short* __restrict__ O)
{
    __shared__ __align__(16) unsigned short Ks[64 * 64];  // [key][d], col-slot XOR-swizzled
    __shared__ __align__(16) unsigned short Vt[64 * 64];  // [d][key], col XOR-swizzled

    const int bh  = blockIdx.x;
    const int b   = bh >> 4;
    const int h   = bh & 15;
    const int qt  = blockIdx.y;
    const int tid = threadIdx.x;
    const int wave = tid >> 6;
    const int lane = tid & 63;
    const int lg   = lane >> 4;    // lane group 0..3
    const int lq   = lane & 15;

    const size_t base = ((size_t)b * SEQ) * D_MODEL + h * DK;
    const int q0  = qt * 64;
    const int qw  = q0 + wave * 16;
    const int myq = qw + lq;

    bf16x8 qf[2];
    {
        const unsigned short* qp = Q + base + (size_t)myq * D_MODEL + lg * 8;
        qf[0] = __builtin_bit_cast(bf16x8, *reinterpret_cast<const short8*>(qp));
        qf[1] = __builtin_bit_cast(bf16x8, *reinterpret_cast<const short8*>(qp + 32));
    }

    f32x4 acc[4];
    for (int i = 0; i < 4; i++)
        for (int r = 0; r < 4; r++) acc[i][r] = 0.f;
    float m_run = -INFINITY, l_run = 0.f;

    const int trow  = tid >> 3;
    const int tslot = tid & 7;

    const int nt = qt + 1;
    for (int t = 0; t < nt; ++t) {
        const int m0 = t * 64;
        __syncthreads();

        {
            const int c0 = (tslot ^ (trow & 7)) * 8;
            gload_lds16(K + base + (size_t)(m0 + trow) * D_MODEL + c0, Ks + wave * 512);
            const int r1 = trow + 32;
            const int c1 = (tslot ^ (r1 & 7)) * 8;
            gload_lds16(K + base + (size_t)(m0 + r1) * D_MODEL + c1, Ks + 2048 + wave * 512);
        }
        for (int p = 0; p < 2; ++p) {
            const int d0 = wave * 8 + p * 32;
            union { uint4 v; unsigned short u[8]; } vb;
            vb.v = *reinterpret_cast<const uint4*>(V + base + (size_t)(m0 + lane) * D_MODEL + d0);
            #pragma unroll
            for (int e = 0; e < 8; ++e) {
                const int d = d0 + e;
                const int addr = d * 128 + ((lane * 2) ^ ((d & 7) << 4));
                *reinterpret_cast<unsigned short*>((char*)Vt + addr) = vb.u[e];
            }
        }
        __syncthreads();

        f32x4 s[4];
        #pragma unroll
        for (int kg = 0; kg < 4; ++kg) {
            for (int r = 0; r < 4; ++r) s[kg][r] = 0.f;
            #pragma unroll
            for (int ks = 0; ks < 2; ++ks) {
                const int row  = kg * 16 + lq;
                const int slot = (ks * 4 + lg) ^ (row & 7);
                bf16x8 kf = __builtin_bit_cast(bf16x8,
                    *reinterpret_cast<const short8*>((const char*)Ks + row * 128 + slot * 16));
                s[kg] = __builtin_amdgcn_mfma_f32_16x16x32_bf16(kf, qf[ks], s[kg], 0, 0, 0);
            }
        }

        float sv[4][4];
        float mx = -INFINITY;
        #pragma unroll
        for (int kg = 0; kg < 4; ++kg)
            #pragma unroll
            for (int r = 0; r < 4; ++r) {
                const int key = m0 + kg * 16 + lg * 4 + r;
                float v = s[kg][r] * 0.125f;
                if (key > myq) v = -INFINITY;
                sv[kg][r] = v;
                mx = fmaxf(mx, v);
            }
        mx = fmaxf(mx, __shfl_xor(mx, 16));
        mx = fmaxf(mx, __shfl_xor(mx, 32));
        const float mnew = fmaxf(m_run, mx);
        const float sc   = __expf(m_run - mnew);
        m_run = mnew;

        float p[4][4];
        float ps = 0.f;
        #pragma unroll
        for (int kg = 0; kg < 4; ++kg)
            #pragma unroll
            for (int r = 0; r < 4; ++r) {
                p[kg][r] = __expf(sv[kg][r] - mnew);
                ps += p[kg][r];
            }
        ps += __shfl_xor(ps, 16);
        ps += __shfl_xor(ps, 32);
        l_run = l_run * sc + ps;

        float scv[4];
        #pragma unroll
        for (int r = 0; r < 4; ++r) scv[r] = __shfl(sc, lg * 4 + r);
        #pragma unroll
        for (int dg = 0; dg < 4; ++dg)
            #pragma unroll
            for (int r = 0; r < 4; ++r) acc[dg][r] *= scv[r];

        #pragma unroll
        for (int ks = 0; ks < 2; ++ks) {
            const unsigned int wlo0 = cvtpk_bf16(p[2*ks][0],   p[2*ks][1]);
            const unsigned int wlo1 = cvtpk_bf16(p[2*ks][2],   p[2*ks][3]);
            const unsigned int whi0 = cvtpk_bf16(p[2*ks+1][0], p[2*ks+1][1]);
            const unsigned int whi1 = cvtpk_bf16(p[2*ks+1][2], p[2*ks+1][3]);
            unsigned int aw[4];
            #pragma unroll
            for (int w = 0; w < 4; ++w) {
                const int src = lq + (((lg & 1) * 2 + (w >> 1)) << 4);
                const unsigned int t0 = __shfl((w & 1) ? wlo1 : wlo0, src);
                const unsigned int t1 = __shfl((w & 1) ? whi1 : whi0, src);
                aw[w] = (lg < 2) ? t0 : t1;
            }
            uint4 awv = make_uint4(aw[0], aw[1], aw[2], aw[3]);
            bf16x8 af = __builtin_bit_cast(bf16x8, awv);
            #pragma unroll
            for (int dg = 0; dg < 4; ++dg) {
                const int d = dg * 16 + lq;
                const int addr = d * 128 + ((ks * 64 + lg * 16) ^ ((d & 7) << 4));
                bf16x8 vf = __builtin_bit_cast(bf16x8,
                    *reinterpret_cast<const short8*>((const char*)Vt + addr));
                acc[dg] = __builtin_amdgcn_mfma_f32_16x16x32_bf16(af, vf, acc[dg], 0, 0, 0);
            }
        }
    }

    float lv[4];
    #pragma unroll
    for (int r = 0; r < 4; ++r) lv[r] = 1.0f / __shfl(l_run, lg * 4 + r);
    #pragma unroll
    for (int dg = 0; dg < 4; ++dg)
        #pragma unroll
        for (int r = 0; r < 4; ++r) {
            const int qrow = qw + lg * 4 + r;
            O[base + (size_t)qrow * D_MODEL + dg * 16 + lq] = f2bf(acc[dg][r] * lv[r]);
        }
}

// ---------------- launch ----------------
extern "C" void kernel_launch(void* const* d_in, const int* in_sizes, int n_in,
                              void* d_out, int out_size, void* d_ws, size_t ws_size,
                              hipStream_t stream) {
    const float* x  = (const float*)d_in[0];
    const float* wq = (const float*)d_in[1];
    const float* wk = (const float*)d_in[2];
    const float* wv = (const float*)d_in[3];
    const float* wo = (const float*)d_in[4];

    char* ws = (char*)d_ws;
    const size_t NXB = (size_t)MROWS * D_MODEL * 2;   // 16 MiB bf16 x
    const size_t NWB = (size_t)D_MODEL * D_MODEL * 2; // 2 MiB bf16 weight

    unsigned short* xb  = (unsigned short*)(ws);
    unsigned short* wqb = (unsigned short*)(ws + NXB);
    unsigned short* wkb = (unsigned short*)(ws + NXB + NWB);
    unsigned short* wvb = (unsigned short*)(ws + NXB + 2 * NWB);
    unsigned short* wob = (unsigned short*)(ws + NXB + 3 * NWB);
    unsigned short* Qb  = (unsigned short*)(ws + NXB + 4 * NWB);
    unsigned short* Kb  = (unsigned short*)(ws + NXB + 4 * NWB + NXB);
    unsigned short* Vb  = (unsigned short*)(ws + NXB + 4 * NWB + 2 * NXB);
    unsigned short* Ab  = (unsigned short*)(ws + NXB + 4 * NWB + 3 * NXB);

    const int NX = MROWS * D_MODEL;
    const int NW = D_MODEL * D_MODEL;

    cvt_bf16<<<NX / 1024, 256, 0, stream>>>(x, xb, NX);
    dim3 gw(NW / 1024, 4, 1);
    cvt_bf16_w<<<gw, 256, 0, stream>>>(wq, wk, wv, wo, wqb, wkb, wvb, wob, NW);

    dim3 gqkv(MROWS / BM, D_MODEL / BN, 3);
    gemm_bt<<<gqkv, 256, 0, stream>>>(xb, wqb, wkb, wvb, Qb, Kb, Vb,
                                      MROWS, D_MODEL, D_MODEL, 0);

    dim3 gattn(BATCH * NHEADS, SEQ / 64, 1);
    attn_mfma<<<gattn, 256, 0, stream>>>(Qb, Kb, Vb, Ab);

    dim3 gout(MROWS / BM, D_MODEL / BN, 1);
    gemm_bt<<<gout, 256, 0, stream>>>(Ab, wob, wob, wob, d_out, d_out, d_out,
                                      MROWS, D_MODEL, D_MODEL, 1);
}

// Round 4
// 220.497 us; speedup vs baseline: 10.6345x; 3.4487x over previous
//
#include <hip/hip_runtime.h>
#include <hip/hip_bf16.h>
#include <cstdint>

#define D_MODEL 1024
#define NHEADS  16
#define DK      64
#define BATCH   4
#define SEQ     2048
#define MROWS   (BATCH * SEQ)   // 8192

typedef __attribute__((ext_vector_type(4))) float  f32x4;
typedef __attribute__((ext_vector_type(8))) __bf16 bf16x8;
typedef __attribute__((ext_vector_type(8))) short  short8;

__device__ __forceinline__ unsigned short f2bf(float f) {
    unsigned int u = __float_as_uint(f);
    unsigned int r = (u + 0x7fffu + ((u >> 16) & 1u)) >> 16;
    return (unsigned short)r;
}

__device__ __forceinline__ unsigned int cvtpk_bf16(float lo, float hi) {
    unsigned int r;
    asm volatile("v_cvt_pk_bf16_f32 %0, %1, %2" : "=v"(r) : "v"(lo), "v"(hi));
    return r;
}

// ---------------- fp32 -> bf16 conversion ----------------
__global__ void cvt_bf16(const float* __restrict__ in, unsigned short* __restrict__ out, int n) {
    int i = (blockIdx.x * 256 + threadIdx.x) * 4;
    if (i >= n) return;
    float4 v = *reinterpret_cast<const float4*>(in + i);
    ushort4 o;
    o.x = f2bf(v.x); o.y = f2bf(v.y); o.z = f2bf(v.z); o.w = f2bf(v.w);
    *reinterpret_cast<ushort4*>(out + i) = o;
}

__global__ void cvt_bf16_w(const float* __restrict__ w0, const float* __restrict__ w1,
                           const float* __restrict__ w2, const float* __restrict__ w3,
                           unsigned short* __restrict__ o0, unsigned short* __restrict__ o1,
                           unsigned short* __restrict__ o2, unsigned short* __restrict__ o3,
                           int n) {
    const int z = blockIdx.y;
    const float* in = (z == 0) ? w0 : (z == 1) ? w1 : (z == 2) ? w2 : w3;
    unsigned short* out = (z == 0) ? o0 : (z == 1) ? o1 : (z == 2) ? o2 : o3;
    int i = (blockIdx.x * 256 + threadIdx.x) * 4;
    if (i >= n) return;
    float4 v = *reinterpret_cast<const float4*>(in + i);
    ushort4 o;
    o.x = f2bf(v.x); o.y = f2bf(v.y); o.z = f2bf(v.z); o.w = f2bf(v.w);
    *reinterpret_cast<ushort4*>(out + i) = o;
}

// ---------------- async global->LDS (16B per lane) ----------------
__device__ __forceinline__ void gload_lds16(const void* g, void* l) {
    __builtin_amdgcn_global_load_lds(
        (const __attribute__((address_space(1))) void*)(uintptr_t)g,
        (__attribute__((address_space(3))) void*)(unsigned int)(uintptr_t)l,
        16, 0, 0);
}

// ---------------- bf16 MFMA GEMM, 2-phase double-buffered pipeline ----------------
// C[M][N] = A[M][K] * Bt[N][K]^T
#define BM 128
#define BN 128
#define BK 32

__global__ __launch_bounds__(256) void gemm_bt(
    const unsigned short* __restrict__ A,
    const unsigned short* __restrict__ B0,
    const unsigned short* __restrict__ B1,
    const unsigned short* __restrict__ B2,
    void* __restrict__ C0, void* __restrict__ C1, void* __restrict__ C2,
    int M, int N, int K, int out_f32)
{
    __shared__ __align__(16) unsigned short As[2][BM * BK];
    __shared__ __align__(16) unsigned short Bs[2][BN * BK];

    const int z = blockIdx.z;
    const unsigned short* Bt = (z == 0) ? B0 : ((z == 1) ? B1 : B2);
    void* C = (z == 0) ? C0 : ((z == 1) ? C1 : C2);

    const int tid  = threadIdx.x;
    const int wave = tid >> 6;
    const int lane = tid & 63;
    const int wr   = wave >> 1;   // 0..1
    const int wc   = wave & 1;    // 0..1
    const int bm   = blockIdx.x * BM;
    const int bn   = blockIdx.y * BN;

    // ALL loops touching acc are fully unrolled -> compile-time indices -> registers
    f32x4 acc[4][4];
    #pragma unroll
    for (int i = 0; i < 4; i++)
        #pragma unroll
        for (int j = 0; j < 4; j++)
            #pragma unroll
            for (int r = 0; r < 4; r++) acc[i][j][r] = 0.f;

    const int srow = tid >> 2;          // 0..63
    const int scol = (tid & 3) * 8;     // 0,8,16,24

    const int kg = (lane >> 4) * 8;
    const int rl = lane & 15;

    const unsigned short* Arow0 = A  + (size_t)(bm + srow) * K + scol;
    const unsigned short* Arow1 = A  + (size_t)(bm + 64 + srow) * K + scol;
    const unsigned short* Brow0 = Bt + (size_t)(bn + srow) * K + scol;
    const unsigned short* Brow1 = Bt + (size_t)(bn + 64 + srow) * K + scol;

    auto STAGE = [&](int buf, int k0) {
        gload_lds16(Arow0 + k0, &As[buf][0] + wave * 512);
        gload_lds16(Arow1 + k0, &As[buf][0] + 2048 + wave * 512);
        gload_lds16(Brow0 + k0, &Bs[buf][0] + wave * 512);
        gload_lds16(Brow1 + k0, &Bs[buf][0] + 2048 + wave * 512);
    };

    auto COMPUTE = [&](int buf) {
        bf16x8 a[4], b[4];
        #pragma unroll
        for (int mi = 0; mi < 4; mi++) {
            short8 t = *reinterpret_cast<const short8*>(&As[buf][(wr * 64 + mi * 16 + rl) * BK + kg]);
            a[mi] = __builtin_bit_cast(bf16x8, t);
        }
        #pragma unroll
        for (int ni = 0; ni < 4; ni++) {
            short8 t = *reinterpret_cast<const short8*>(&Bs[buf][(wc * 64 + ni * 16 + rl) * BK + kg]);
            b[ni] = __builtin_bit_cast(bf16x8, t);
        }
        #pragma unroll
        for (int mi = 0; mi < 4; mi++)
            #pragma unroll
            for (int ni = 0; ni < 4; ni++)
                acc[mi][ni] = __builtin_amdgcn_mfma_f32_16x16x32_bf16(a[mi], b[ni], acc[mi][ni], 0, 0, 0);
    };

    const int NT = K / BK;

    STAGE(0, 0);
    __syncthreads();

    int cur = 0;
    for (int t = 0; t < NT - 1; ++t) {
        STAGE(cur ^ 1, (t + 1) * BK);
        COMPUTE(cur);
        __syncthreads();
        cur ^= 1;
    }
    COMPUTE(cur);

    const int rg = (lane >> 4) * 4;
    if (out_f32) {
        #pragma unroll
        for (int mi = 0; mi < 4; mi++)
            #pragma unroll
            for (int ni = 0; ni < 4; ni++)
                #pragma unroll
                for (int r = 0; r < 4; r++) {
                    int row = bm + wr * 64 + mi * 16 + rg + r;
                    int col = bn + wc * 64 + ni * 16 + rl;
                    ((float*)C)[(size_t)row * N + col] = acc[mi][ni][r];
                }
    } else {
        #pragma unroll
        for (int mi = 0; mi < 4; mi++)
            #pragma unroll
            for (int ni = 0; ni < 4; ni++)
                #pragma unroll
                for (int r = 0; r < 4; r++) {
                    int row = bm + wr * 64 + mi * 16 + rg + r;
                    int col = bn + wc * 64 + ni * 16 + rl;
                    ((unsigned short*)C)[(size_t)row * N + col] = f2bf(acc[mi][ni][r]);
                }
    }
}

// ---------------- MFMA causal flash attention ----------------
__global__ __launch_bounds__(256) void attn_mfma(
    const unsigned short* __restrict__ Q,
    const unsigned short* __restrict__ K,
    const unsigned short* __restrict__ V,
    unsigned short* __restrict__ O)
{
    __shared__ __align__(16) unsigned short Ks[64 * 64];  // [key][d], col-slot XOR-swizzled
    __shared__ __align__(16) unsigned short Vt[64 * 64];  // [d][key], col XOR-swizzled

    const int bh  = blockIdx.x;
    const int b   = bh >> 4;
    const int h   = bh & 15;
    const int qt  = blockIdx.y;
    const int tid = threadIdx.x;
    const int wave = tid >> 6;
    const int lane = tid & 63;
    const int lg   = lane >> 4;    // lane group 0..3
    const int lq   = lane & 15;

    const size_t base = ((size_t)b * SEQ) * D_MODEL + h * DK;
    const int q0  = qt * 64;
    const int qw  = q0 + wave * 16;
    const int myq = qw + lq;

    bf16x8 qf[2];
    {
        const unsigned short* qp = Q + base + (size_t)myq * D_MODEL + lg * 8;
        qf[0] = __builtin_bit_cast(bf16x8, *reinterpret_cast<const short8*>(qp));
        qf[1] = __builtin_bit_cast(bf16x8, *reinterpret_cast<const short8*>(qp + 32));
    }

    f32x4 acc[4];
    #pragma unroll
    for (int i = 0; i < 4; i++)
        #pragma unroll
        for (int r = 0; r < 4; r++) acc[i][r] = 0.f;
    float m_run = -INFINITY, l_run = 0.f;

    const int trow  = tid >> 3;
    const int tslot = tid & 7;

    const int nt = qt + 1;
    for (int t = 0; t < nt; ++t) {
        const int m0 = t * 64;
        __syncthreads();

        {
            const int c0 = (tslot ^ (trow & 7)) * 8;
            gload_lds16(K + base + (size_t)(m0 + trow) * D_MODEL + c0, Ks + wave * 512);
            const int r1 = trow + 32;
            const int c1 = (tslot ^ (r1 & 7)) * 8;
            gload_lds16(K + base + (size_t)(m0 + r1) * D_MODEL + c1, Ks + 2048 + wave * 512);
        }
        #pragma unroll
        for (int p = 0; p < 2; ++p) {
            const int d0 = wave * 8 + p * 32;
            union { uint4 v; unsigned short u[8]; } vb;
            vb.v = *reinterpret_cast<const uint4*>(V + base + (size_t)(m0 + lane) * D_MODEL + d0);
            #pragma unroll
            for (int e = 0; e < 8; ++e) {
                const int d = d0 + e;
                const int addr = d * 128 + ((lane * 2) ^ ((d & 7) << 4));
                *reinterpret_cast<unsigned short*>((char*)Vt + addr) = vb.u[e];
            }
        }
        __syncthreads();

        f32x4 s[4];
        #pragma unroll
        for (int kg = 0; kg < 4; ++kg) {
            #pragma unroll
            for (int r = 0; r < 4; ++r) s[kg][r] = 0.f;
            #pragma unroll
            for (int ks = 0; ks < 2; ++ks) {
                const int row  = kg * 16 + lq;
                const int slot = (ks * 4 + lg) ^ (row & 7);
                bf16x8 kf = __builtin_bit_cast(bf16x8,
                    *reinterpret_cast<const short8*>((const char*)Ks + row * 128 + slot * 16));
                s[kg] = __builtin_amdgcn_mfma_f32_16x16x32_bf16(kf, qf[ks], s[kg], 0, 0, 0);
            }
        }

        float sv[4][4];
        float mx = -INFINITY;
        #pragma unroll
        for (int kg = 0; kg < 4; ++kg)
            #pragma unroll
            for (int r = 0; r < 4; ++r) {
                const int key = m0 + kg * 16 + lg * 4 + r;
                float v = s[kg][r] * 0.125f;
                if (key > myq) v = -INFINITY;
                sv[kg][r] = v;
                mx = fmaxf(mx, v);
            }
        mx = fmaxf(mx, __shfl_xor(mx, 16));
        mx = fmaxf(mx, __shfl_xor(mx, 32));
        const float mnew = fmaxf(m_run, mx);
        const float sc   = __expf(m_run - mnew);
        m_run = mnew;

        float p[4][4];
        float ps = 0.f;
        #pragma unroll
        for (int kg = 0; kg < 4; ++kg)
            #pragma unroll
            for (int r = 0; r < 4; ++r) {
                p[kg][r] = __expf(sv[kg][r] - mnew);
                ps += p[kg][r];
            }
        ps += __shfl_xor(ps, 16);
        ps += __shfl_xor(ps, 32);
        l_run = l_run * sc + ps;

        float scv[4];
        #pragma unroll
        for (int r = 0; r < 4; ++r) scv[r] = __shfl(sc, lg * 4 + r);
        #pragma unroll
        for (int dg = 0; dg < 4; ++dg)
            #pragma unroll
            for (int r = 0; r < 4; ++r) acc[dg][r] *= scv[r];

        #pragma unroll
        for (int ks = 0; ks < 2; ++ks) {
            const unsigned int wlo0 = cvtpk_bf16(p[2*ks][0],   p[2*ks][1]);
            const unsigned int wlo1 = cvtpk_bf16(p[2*ks][2],   p[2*ks][3]);
            const unsigned int whi0 = cvtpk_bf16(p[2*ks+1][0], p[2*ks+1][1]);
            const unsigned int whi1 = cvtpk_bf16(p[2*ks+1][2], p[2*ks+1][3]);
            unsigned int aw[4];
            #pragma unroll
            for (int w = 0; w < 4; ++w) {
                const int src = lq + (((lg & 1) * 2 + (w >> 1)) << 4);
                const unsigned int t0 = __shfl((w & 1) ? wlo1 : wlo0, src);
                const unsigned int t1 = __shfl((w & 1) ? whi1 : whi0, src);
                aw[w] = (lg < 2) ? t0 : t1;
            }
            uint4 awv = make_uint4(aw[0], aw[1], aw[2], aw[3]);
            bf16x8 af = __builtin_bit_cast(bf16x8, awv);
            #pragma unroll
            for (int dg = 0; dg < 4; ++dg) {
                const int d = dg * 16 + lq;
                const int addr = d * 128 + ((ks * 64 + lg * 16) ^ ((d & 7) << 4));
                bf16x8 vf = __builtin_bit_cast(bf16x8,
                    *reinterpret_cast<const short8*>((const char*)Vt + addr));
                acc[dg] = __builtin_amdgcn_mfma_f32_16x16x32_bf16(af, vf, acc[dg], 0, 0, 0);
            }
        }
    }

    float lv[4];
    #pragma unroll
    for (int r = 0; r < 4; ++r) lv[r] = 1.0f / __shfl(l_run, lg * 4 + r);
    #pragma unroll
    for (int dg = 0; dg < 4; ++dg)
        #pragma unroll
        for (int r = 0; r < 4; ++r) {
            const int qrow = qw + lg * 4 + r;
            O[base + (size_t)qrow * D_MODEL + dg * 16 + lq] = f2bf(acc[dg][r] * lv[r]);
        }
}

// ---------------- launch ----------------
extern "C" void kernel_launch(void* const* d_in, const int* in_sizes, int n_in,
                              void* d_out, int out_size, void* d_ws, size_t ws_size,
                              hipStream_t stream) {
    const float* x  = (const float*)d_in[0];
    const float* wq = (const float*)d_in[1];
    const float* wk = (const float*)d_in[2];
    const float* wv = (const float*)d_in[3];
    const float* wo = (const float*)d_in[4];

    char* ws = (char*)d_ws;
    const size_t NXB = (size_t)MROWS * D_MODEL * 2;   // 16 MiB bf16 x
    const size_t NWB = (size_t)D_MODEL * D_MODEL * 2; // 2 MiB bf16 weight

    unsigned short* xb  = (unsigned short*)(ws);
    unsigned short* wqb = (unsigned short*)(ws + NXB);
    unsigned short* wkb = (unsigned short*)(ws + NXB + NWB);
    unsigned short* wvb = (unsigned short*)(ws + NXB + 2 * NWB);
    unsigned short* wob = (unsigned short*)(ws + NXB + 3 * NWB);
    unsigned short* Qb  = (unsigned short*)(ws + NXB + 4 * NWB);
    unsigned short* Kb  = (unsigned short*)(ws + NXB + 4 * NWB + NXB);
    unsigned short* Vb  = (unsigned short*)(ws + NXB + 4 * NWB + 2 * NXB);
    unsigned short* Ab  = (unsigned short*)(ws + NXB + 4 * NWB + 3 * NXB);

    const int NX = MROWS * D_MODEL;
    const int NW = D_MODEL * D_MODEL;

    cvt_bf16<<<NX / 1024, 256, 0, stream>>>(x, xb, NX);
    dim3 gw(NW / 1024, 4, 1);
    cvt_bf16_w<<<gw, 256, 0, stream>>>(wq, wk, wv, wo, wqb, wkb, wvb, wob, NW);

    dim3 gqkv(MROWS / BM, D_MODEL / BN, 3);
    gemm_bt<<<gqkv, 256, 0, stream>>>(xb, wqb, wkb, wvb, Qb, Kb, Vb,
                                      MROWS, D_MODEL, D_MODEL, 0);

    dim3 gattn(BATCH * NHEADS, SEQ / 64, 1);
    attn_mfma<<<gattn, 256, 0, stream>>>(Qb, Kb, Vb, Ab);

    dim3 gout(MROWS / BM, D_MODEL / BN, 1);
    gemm_bt<<<gout, 256, 0, stream>>>(Ab, wob, wob, wob, d_out, d_out, d_out,
                                      MROWS, D_MODEL, D_MODEL, 1);
}